// Round 3
// baseline (301.051 us; speedup 1.0000x reference)
//
#include <hip/hip_runtime.h>
#include <hip/hip_bf16.h>
#include <stdint.h>

// Problem constants: B=128, S=512, I=128, Hd=512, G=3*Hd=1536, M=B*S=65536.
// Inputs/outputs FP32. Convert x/w_emb/w_ih to bf16 once (one fused kernel),
// bf16 MFMA GEMMs with fp32 accumulate, fp32 output.
//
// gru_gemm (round 3): 3-slot LDS ring, prefetch distance 2 K-tiles, ONE
// counted s_waitcnt vmcnt(4) per tile (never drains to 0 in the loop),
// raw s_barrier (no __syncthreads vmcnt-0 drain), setprio around MFMA.
// BK=32 tiles: LDS rows are 32 bf16 = 64B; global-source swizzle places
// global col-chunk (t^(row&3)) at LDS slot t so b128 fragment reads are
// 2-way-max bank aliased (free, m136).
#define M_TOT   65536
#define I_DIM   128
#define HD      512
#define HOFF    33488896   // 128*511*512, element offset of h_last in d_out
#define HROW    261632     // 511*512, per-b row stride of H

typedef __bf16 bf16x8 __attribute__((ext_vector_type(8)));
typedef float f32x4 __attribute__((ext_vector_type(4)));

struct __align__(8) bf16x4_t { __hip_bfloat16 v[4]; };

// async global->LDS, 16B per lane (lane-scatter base+lane*16, m104/m108).
__device__ __forceinline__ void async_load16(const void* g, void* l) {
  __builtin_amdgcn_global_load_lds(
      (const __attribute__((address_space(1))) void*)g,
      (__attribute__((address_space(3))) void*)l, 16, 0, 0);
}

// v_rcp_f32: rel err 2^-22 — far below the 1.4e-2 abs threshold.
__device__ __forceinline__ float fastrcp(float x) {
  return __builtin_amdgcn_rcpf(x);
}
__device__ __forceinline__ float sigf(float x) {
  return fastrcp(1.0f + __expf(-x));
}
__device__ __forceinline__ float tanhfast(float x) {
  return 1.0f - 2.0f * fastrcp(__expf(2.0f * x) + 1.0f);
}

// ---------------------------------------------------------------------------
// Fused fp32 -> bf16 conversion for x, w_emb, w_ih (one launch).
// ---------------------------------------------------------------------------
#define N4_X   2097152                 // 65536*128/4
#define N4_WE  (N4_X + 16384)          // + 512*128/4
#define N4_WI  (N4_WE + 196608)        // + 1536*512/4
__global__ void cvt_all(const float* __restrict__ x,
                        const float* __restrict__ we,
                        const float* __restrict__ wi,
                        __hip_bfloat16* __restrict__ xb,
                        __hip_bfloat16* __restrict__ web,
                        __hip_bfloat16* __restrict__ wib) {
  const int i = blockIdx.x * blockDim.x + threadIdx.x;
  const float4* src;
  bf16x4_t* dst;
  int off;
  if (i < N4_X)       { src = (const float4*)x;  dst = (bf16x4_t*)xb;  off = i; }
  else if (i < N4_WE) { src = (const float4*)we; dst = (bf16x4_t*)web; off = i - N4_X; }
  else if (i < N4_WI) { src = (const float4*)wi; dst = (bf16x4_t*)wib; off = i - N4_WE; }
  else return;
  const float4 v = src[off];
  bf16x4_t o;
  o.v[0] = __float2bfloat16(v.x);
  o.v[1] = __float2bfloat16(v.y);
  o.v[2] = __float2bfloat16(v.z);
  o.v[3] = __float2bfloat16(v.w);
  dst[off] = o;
}

// ---------------------------------------------------------------------------
// Kernel 1: emb[m,h] = sum_i x[m,i]*w_emb[h,i] + b_emb[h]   (bf16 out -> ws)
// M=65536, N=512, K=128. Tile 128x128, BK=64, 2 K-tiles. 4 waves, 64x64 each.
// (unchanged — isolating the gru_gemm schedule change)
// ---------------------------------------------------------------------------
__device__ __forceinline__ void emb_stage(const __hip_bfloat16* __restrict__ x,
                                          const __hip_bfloat16* __restrict__ w_emb,
                                          int m0, int n0, int k,
                                          __hip_bfloat16* As, __hip_bfloat16* Bs,
                                          int w, int lrow, int gc) {
#pragma unroll
  for (int c = 0; c < 4; ++c) {
    const int chunk = w * 4 + c;
    const int row = chunk * 8 + lrow;
    async_load16(x + (size_t)(m0 + row) * I_DIM + k + gc, (void*)&As[chunk * 512]);
    async_load16(w_emb + (size_t)(n0 + row) * I_DIM + k + gc, (void*)&Bs[chunk * 512]);
  }
}

__global__ __launch_bounds__(256, 2) void emb_gemm(
    const __hip_bfloat16* __restrict__ x,      // (65536,128) bf16 (ws)
    const __hip_bfloat16* __restrict__ w_emb,  // (512,128)  N x K, bf16 (ws)
    const float* __restrict__ b_emb,           // (512) fp32
    __hip_bfloat16* __restrict__ emb)          // (65536,512) bf16 (ws)
{
  // 2 buffers x (As 8192 el ++ Bs 8192 el) = 65536 B -> 2 blocks/CU
  __shared__ __align__(16) __hip_bfloat16 smem[32768];

  const int tid  = threadIdx.x;
  const int w    = tid >> 6;
  const int lane = tid & 63;
  const int m0 = blockIdx.x * 128;
  const int n0 = blockIdx.y * 128;
  const int wm = (w >> 1) * 64;
  const int wn = (w & 1) * 64;
  const int lrow = lane >> 3;              // 0..7 (row within 8-row chunk)
  const int gc   = ((lane & 7) ^ lrow) * 8;  // swizzled global element offset
  const int l15 = lane & 15;
  const int q   = lane >> 4;
  const int sx  = l15 & 7;                 // row&7 for fragment rows

  f32x4 acc[4][4];
#pragma unroll
  for (int i = 0; i < 4; ++i)
#pragma unroll
    for (int j = 0; j < 4; ++j) acc[i][j] = (f32x4)0.0f;

  // prologue: stage tile 0 -> buf0; __syncthreads drains vmcnt.
  emb_stage(x, w_emb, m0, n0, 0, smem, smem + 8192, w, lrow, gc);
  __syncthreads();

#pragma unroll
  for (int t = 0; t < 2; ++t) {
    const __hip_bfloat16* As = smem + (t & 1) * 16384;
    const __hip_bfloat16* Bs = As + 8192;
    if (t == 0)  // prefetch tile 1 -> buf1 while computing tile 0
      emb_stage(x, w_emb, m0, n0, 64, smem + 16384, smem + 16384 + 8192,
                w, lrow, gc);
    __builtin_amdgcn_sched_barrier(0);     // pin stage issue at tile top
#pragma unroll
    for (int ks = 0; ks < 2; ++ks) {
      const int s = ((ks * 4 + q) ^ sx) * 8;   // swizzled LDS chunk
      bf16x8 af[4], bfr[4];
#pragma unroll
      for (int mi = 0; mi < 4; ++mi)
        af[mi] = *(const bf16x8*)&As[(wm + mi * 16 + l15) * 64 + s];
#pragma unroll
      for (int ni = 0; ni < 4; ++ni)
        bfr[ni] = *(const bf16x8*)&Bs[(wn + ni * 16 + l15) * 64 + s];
      __builtin_amdgcn_s_setprio(1);
#pragma unroll
      for (int ni = 0; ni < 4; ++ni)
#pragma unroll
        for (int mi = 0; mi < 4; ++mi)
          acc[mi][ni] = __builtin_amdgcn_mfma_f32_16x16x32_bf16(
              af[mi], bfr[ni], acc[mi][ni], 0, 0, 0);
      __builtin_amdgcn_s_setprio(0);
    }
    if (t == 0) __syncthreads();   // vmcnt(0)+lgkmcnt(0)+barrier: buf1 ready
  }

  // Epilogue: +b_emb, repack wave-private 64x64 tile through LDS, 16B stores.
  // ebuf lives in buf0; last tile read buf1 -> disjoint, no barrier needed.
  // C/D layout: col=lane&15, row=q*4+reg (m89).
  __hip_bfloat16* ebuf = &smem[w * 64 * 64];   // 8KB per wave, wave-private
#pragma unroll
  for (int ni = 0; ni < 4; ++ni) {
    const float bias = b_emb[n0 + wn + ni * 16 + l15];
#pragma unroll
    for (int mi = 0; mi < 4; ++mi)
#pragma unroll
      for (int r = 0; r < 4; ++r)
        ebuf[(mi * 16 + q * 4 + r) * 64 + ni * 16 + l15] =
            __float2bfloat16(acc[mi][ni][r] + bias);
  }
  // wave-private buffer: compiler-inserted lgkmcnt orders write->read
#pragma unroll
  for (int i = 0; i < 8; ++i) {
    const int row  = i * 8 + (lane >> 3);
    const int colb = (lane & 7) * 8;
    const bf16x8 v = *(const bf16x8*)&ebuf[row * 64 + colb];
    *(bf16x8*)&emb[(size_t)(m0 + wm + row) * HD + n0 + wn + colb] = v;
  }
}

// ---------------------------------------------------------------------------
// Kernel 2: gi[m, g*512+h] = sum_h' emb[m,h']*w_ih[g*512+h, h'] ; gate math.
// Round-3 geometry: block = 128 M-rows x 128 h-cols x 3 gates; BK=32,
// 16 K-tiles; 512 threads = 8 waves (4M x 2N): wave = 32M x 64h x 3g
// -> acc[3][2][4] = 24 f32x4 = 96 VGPR.
// LDS: 3-slot ring, slot = A(128x32, 8KB) ++ B(384x32, 24KB) = 32KB; 96KB.
// Per wave per tile: 4 uniform global_load_lds (1 A chunk + 3 B chunks).
// Schedule per tile T: stage(T+2 -> slot (T+2)%3); ds_read frags(slot T%3);
// MFMA x24 (setprio); s_waitcnt vmcnt(4)  [= T+1 complete, T+2 in flight];
// s_barrier. Loads get ~2 tiles of latency budget; no vmcnt(0) in the loop.
// WAR safety: slot (T+2)%3's last readers ran in tile T-1; every ds_read is
// an MFMA operand, so compiler lgkm waits drain reads before T-1's barrier.
// ---------------------------------------------------------------------------
__device__ __forceinline__ void gru_stage32(const __hip_bfloat16* __restrict__ emb,
                                            const __hip_bfloat16* __restrict__ w_ih,
                                            int m0, int h0, int k,
                                            __hip_bfloat16* As, __hip_bfloat16* Bs,
                                            int w, int rin, int gc) {
  // A: 8 chunks of 16 rows x 32 cols (1024B); wave w stages chunk w.
  async_load16(emb + (size_t)(m0 + w * 16 + rin) * HD + k + gc,
               (void*)&As[w * 512]);
  // B: 24 chunks; wave w stages chunks w, w+8, w+16.
#pragma unroll
  for (int j = 0; j < 3; ++j) {
    const int c = w + j * 8;           // 0..23
    const int r = c * 16 + rin;        // 0..383
    const int g = r >> 7;              // gate
    const int hh = r & 127;            // h within gate tile
    async_load16(w_ih + (size_t)(g * HD + h0 + hh) * HD + k + gc,
                 (void*)&Bs[c * 512]);
  }
}

__global__ __launch_bounds__(512, 2) void gru_gemm(
    const __hip_bfloat16* __restrict__ emb,   // (65536,512) bf16 (ws)
    const __hip_bfloat16* __restrict__ w_ih,  // (1536,512) N x K, bf16 (ws)
    const float* __restrict__ b_ih,           // (1536) fp32
    const float* __restrict__ b_hh,           // (1536) fp32
    float* __restrict__ out)                  // H(128,511,512) ++ h_last(128,512) fp32
{
  __shared__ __align__(16) char smem[98304];   // 3 x (A 8KB ++ B 24KB)

  const int tid  = threadIdx.x;
  const int w    = tid >> 6;                 // 0..7
  const int lane = tid & 63;
  const int m0 = blockIdx.x * 128;
  const int h0 = blockIdx.y * 128;
  const int wm = (w >> 1) * 32;              // 0,32,64,96
  const int wn = (w & 1) * 64;               // 0,64
  const int rin = lane >> 2;                 // 0..15, row within 16-row chunk
  const int gc  = (((lane & 3) ^ (rin & 3))) * 8;  // swizzled global col elems
  const int l15 = lane & 15;
  const int q   = lane >> 4;                 // 0..3, K-subchunk of the frag
  const int sA  = (q ^ (l15 & 3)) * 8;       // swizzled LDS col elems (row&3=l15&3)

  f32x4 acc[3][2][4];
#pragma unroll
  for (int g = 0; g < 3; ++g)
#pragma unroll
    for (int i = 0; i < 2; ++i)
#pragma unroll
      for (int j = 0; j < 4; ++j) acc[g][i][j] = (f32x4)0.0f;

  // Prologue: stage tiles 0 and 1 (FIFO: t0's 4 loads, then t1's 4).
  gru_stage32(emb, w_ih, m0, h0, 0,
              (__hip_bfloat16*)smem, (__hip_bfloat16*)(smem + 8192),
              w, rin, gc);
  gru_stage32(emb, w_ih, m0, h0, 32,
              (__hip_bfloat16*)(smem + 32768), (__hip_bfloat16*)(smem + 32768 + 8192),
              w, rin, gc);
  asm volatile("s_waitcnt vmcnt(4)" ::: "memory");   // t0 done (t1 in flight)
  __builtin_amdgcn_s_barrier();
  asm volatile("" ::: "memory");

#pragma unroll
  for (int t = 0; t < 16; ++t) {
    const __hip_bfloat16* As = (const __hip_bfloat16*)(smem + (t % 3) * 32768);
    const __hip_bfloat16* Bs = As + 4096;    // +8192 bytes
    if (t < 14) {
      __hip_bfloat16* An = (__hip_bfloat16*)(smem + ((t + 2) % 3) * 32768);
      gru_stage32(emb, w_ih, m0, h0, (t + 2) * 32, An, An + 4096, w, rin, gc);
    }
    __builtin_amdgcn_sched_barrier(0);       // keep stage issue at tile top

    const bf16x8 af0 = *(const bf16x8*)&As[(wm + l15) * 32 + sA];
    const bf16x8 af1 = *(const bf16x8*)&As[(wm + 16 + l15) * 32 + sA];
    __builtin_amdgcn_s_setprio(1);
#pragma unroll
    for (int g = 0; g < 3; ++g)
#pragma unroll
      for (int ni = 0; ni < 4; ++ni) {
        const bf16x8 bfv =
            *(const bf16x8*)&Bs[(g * 128 + wn + ni * 16 + l15) * 32 + sA];
        acc[g][0][ni] = __builtin_amdgcn_mfma_f32_16x16x32_bf16(
            af0, bfv, acc[g][0][ni], 0, 0, 0);
        acc[g][1][ni] = __builtin_amdgcn_mfma_f32_16x16x32_bf16(
            af1, bfv, acc[g][1][ni], 0, 0, 0);
      }
    __builtin_amdgcn_s_setprio(0);

    if (t < 14)       asm volatile("s_waitcnt vmcnt(4)" ::: "memory");
    else if (t == 14) asm volatile("s_waitcnt vmcnt(0)" ::: "memory");
    if (t < 15) {
      __builtin_amdgcn_s_barrier();
      asm volatile("" ::: "memory");
    }
  }
  __syncthreads();   // full drain once; smem now reusable for epilogue

  // Epilogue: gate math (v_rcp), repack wave tile (32M x 64h fp32) through
  // LDS stride 72 floats (288B, 16B-aligned for float4 reads), float4 out.
  // Per wave 32*72*4 = 9216 B, 8 waves = 73728 <= 98304.
  float* obuf = (float*)(smem + w * 9216);
#pragma unroll
  for (int ni = 0; ni < 4; ++ni) {
    const int col = h0 + wn + ni * 16 + l15;
    const float br = b_ih[col] + b_hh[col];
    const float bz = b_ih[HD + col] + b_hh[HD + col];
    const float bn = b_ih[2 * HD + col];
    const float bhn = b_hh[2 * HD + col];
#pragma unroll
    for (int mi = 0; mi < 2; ++mi) {
#pragma unroll
      for (int r = 0; r < 4; ++r) {
        const float rr = sigf(acc[0][mi][ni][r] + br);
        const float zz = sigf(acc[1][mi][ni][r] + bz);
        const float nn = tanhfast(acc[2][mi][ni][r] + bn + rr * bhn);
        obuf[(mi * 16 + q * 4 + r) * 72 + ni * 16 + l15] = (1.0f - zz) * nn;
      }
    }
  }
  // wave-private region: compiler-inserted lgkmcnt orders write->read
  const int srow = lane >> 4;        // 0..3
  const int scol = (lane & 15) * 4;  // 0,4,...,60
#pragma unroll
  for (int i = 0; i < 8; ++i) {
    const int row = i * 4 + srow;    // m_local 0..31
    const float4 v = *(const float4*)&obuf[row * 72 + scol];
    const int m = m0 + wm + row;
    const int b = m >> 9;            // m / 512
    const int s = m & 511;           // m % 512
    float* dst = (s < 511)
        ? out + (size_t)b * HROW + (size_t)s * HD + h0 + wn + scol
        : out + (size_t)HOFF + (size_t)b * HD + h0 + wn + scol;
    *(float4*)dst = v;
  }
}

extern "C" void kernel_launch(void* const* d_in, const int* in_sizes, int n_in,
                              void* d_out, int out_size, void* d_ws, size_t ws_size,
                              hipStream_t stream) {
  const float* x_f     = (const float*)d_in[0];   // (128,512,128)
  const float* w_emb_f = (const float*)d_in[1];   // (512,128)
  const float* b_emb   = (const float*)d_in[2];   // (512)
  const float* w_ih_f  = (const float*)d_in[3];   // (1536,512)
  const float* b_ih    = (const float*)d_in[4];   // (1536)
  const float* b_hh    = (const float*)d_in[5];   // (1536)
  float* out = (float*)d_out;

  // ws layout (bytes):
  //   [0, 64Mi)            emb bf16 (65536*512*2)
  //   [64Mi, +16Mi)        x bf16   (65536*128*2)
  //   [80Mi, +128Ki)       w_emb bf16
  //   [80Mi+128Ki, +1.5Mi) w_ih bf16
  char* ws = (char*)d_ws;
  __hip_bfloat16* emb_bf   = (__hip_bfloat16*)(ws);
  __hip_bfloat16* x_bf     = (__hip_bfloat16*)(ws + 67108864);
  __hip_bfloat16* w_emb_bf = (__hip_bfloat16*)(ws + 67108864 + 16777216);
  __hip_bfloat16* w_ih_bf  = (__hip_bfloat16*)(ws + 67108864 + 16777216 + 131072);

  cvt_all<<<(N4_WI + 255) / 256, 256, 0, stream>>>(
      x_f, w_emb_f, w_ih_f, x_bf, w_emb_bf, w_ih_bf);

  emb_gemm<<<dim3(M_TOT / 128, HD / 128), 256, 0, stream>>>(
      x_bf, w_emb_bf, b_emb, emb_bf);
  gru_gemm<<<dim3(M_TOT / 128, HD / 128), 512, 0, stream>>>(
      emb_bf, w_ih_bf, b_ih, b_hh, out);
}

// Round 4
// 212.792 us; speedup vs baseline: 1.4148x; 1.4148x over previous
//
#include <hip/hip_runtime.h>
#include <hip/hip_bf16.h>
#include <stdint.h>

// Problem: B=128, S=512, I=128, Hd=512, G=3*Hd=1536, M=B*S=65536.
//
// ALGEBRAIC FUSION (round 4): the pre-gate computation is affine, so
//   gi = (x @ W_emb^T + b_emb) @ W_ih^T + b_ih
//      =  x @ (W_ih @ W_emb)^T + (W_ih @ b_emb + b_ih)
// Precompute W_fused (1536x128) and b_fused (1536) once (tiny), then ONE
// bf16 MFMA GEMM with K=128 (25.8 GFLOP vs the old 111.6 GFLOP two-GEMM
// chain), fused gate math + strided store epilogue.
//
// All GEMM structures below are the r0/r2-proven ones (swizzled
// global_load_lds staging, dbuf, 2 blocks/CU, one barrier per K-tile).
#define M_TOT   65536
#define I_DIM   128
#define HD      512
#define HOFF    33488896   // 128*511*512, element offset of h_last in d_out
#define HROW    261632     // 511*512, per-b row stride of H

typedef __bf16 bf16x8 __attribute__((ext_vector_type(8)));
typedef float f32x4 __attribute__((ext_vector_type(4)));

struct __align__(8) bf16x4_t { __hip_bfloat16 v[4]; };

// async global->LDS, 16B per lane (lane-scatter base+lane*16, m104/m108).
__device__ __forceinline__ void async_load16(const void* g, void* l) {
  __builtin_amdgcn_global_load_lds(
      (const __attribute__((address_space(1))) void*)g,
      (__attribute__((address_space(3))) void*)l, 16, 0, 0);
}

// v_rcp_f32: rel err 2^-22 — far below the 1.4e-2 abs threshold.
__device__ __forceinline__ float fastrcp(float x) {
  return __builtin_amdgcn_rcpf(x);
}
__device__ __forceinline__ float sigf(float x) {
  return fastrcp(1.0f + __expf(-x));
}
__device__ __forceinline__ float tanhfast(float x) {
  return 1.0f - 2.0f * fastrcp(__expf(2.0f * x) + 1.0f);
}

// ---------------------------------------------------------------------------
// prep: (a) x f32->bf16, (b) w_ih f32->bf16, (c) w_emb f32 -> w_embT bf16
// (transposed to (128,512) so the fuse GEMM has K contiguous on both sides),
// (d) b_fused[g] = b_ih[g] + dot(w_ih[g,:], b_emb)  (one wave per g).
// ---------------------------------------------------------------------------
#define PB_X   8192          // 8192*256 float4 = 2097152 = 65536*128/4
#define PB_WI  768           // 768*256   float4 = 196608 = 1536*512/4
#define PB_TR  16            // 16 blocks * 8 i-rows = 128
#define PB_BF  384           // 384 blocks * 4 waves = 1536 g
__global__ void prep(const float* __restrict__ x,
                     const float* __restrict__ we,
                     const float* __restrict__ wi,
                     const float* __restrict__ b_emb,
                     const float* __restrict__ b_ih,
                     __hip_bfloat16* __restrict__ xb,
                     __hip_bfloat16* __restrict__ weT,
                     __hip_bfloat16* __restrict__ wib,
                     float* __restrict__ bfu) {
  const int bid = blockIdx.x;
  const int tid = threadIdx.x;
  if (bid < PB_X) {                          // x cvt
    const int i = bid * 256 + tid;
    const float4 v = ((const float4*)x)[i];
    bf16x4_t o;
    o.v[0] = __float2bfloat16(v.x); o.v[1] = __float2bfloat16(v.y);
    o.v[2] = __float2bfloat16(v.z); o.v[3] = __float2bfloat16(v.w);
    ((bf16x4_t*)xb)[i] = o;
  } else if (bid < PB_X + PB_WI) {           // w_ih cvt
    const int i = (bid - PB_X) * 256 + tid;
    const float4 v = ((const float4*)wi)[i];
    bf16x4_t o;
    o.v[0] = __float2bfloat16(v.x); o.v[1] = __float2bfloat16(v.y);
    o.v[2] = __float2bfloat16(v.z); o.v[3] = __float2bfloat16(v.w);
    ((bf16x4_t*)wib)[i] = o;
  } else if (bid < PB_X + PB_WI + PB_TR) {   // w_emb transpose+cvt
    const int b = bid - (PB_X + PB_WI);
    const int i  = b * 8 + (tid >> 5);       // output row (i), 0..127
    const int h0 = (tid & 31) * 16;          // output col chunk (h)
    bf16x8 v0, v1;
#pragma unroll
    for (int j = 0; j < 8; ++j) {
      v0[j] = (__bf16)we[(size_t)(h0 + j) * I_DIM + i];
      v1[j] = (__bf16)we[(size_t)(h0 + 8 + j) * I_DIM + i];
    }
    *(bf16x8*)&weT[(size_t)i * HD + h0] = v0;
    *(bf16x8*)&weT[(size_t)i * HD + h0 + 8] = v1;
  } else {                                   // b_fused: one wave per g
    const int g = (bid - (PB_X + PB_WI + PB_TR)) * 4 + (tid >> 6);
    const int lane = tid & 63;
    const float4* row = (const float4*)(wi + (size_t)g * HD);
    const float4* be  = (const float4*)b_emb;
    float s = 0.0f;
#pragma unroll
    for (int j = 0; j < 2; ++j) {
      const float4 a = row[lane * 2 + j];
      const float4 b = be[lane * 2 + j];
      s += a.x * b.x + a.y * b.y + a.z * b.z + a.w * b.w;
    }
#pragma unroll
    for (int off = 32; off > 0; off >>= 1) s += __shfl_down(s, off);
    if (lane == 0) bfu[g] = s + b_ih[g];
  }
}

// ---------------------------------------------------------------------------
// fuse_gemm: W_fused[g,i] = sum_h w_ih_bf[g,h] * w_embT_bf[i,h]
// M=1536, N=128, K=512. Tile 128x128, 12 blocks, 4 waves (64x64 each),
// BK=64 dbuf (2x32KB LDS), one __syncthreads per tile. bf16 out (1536,128).
// ---------------------------------------------------------------------------
__global__ __launch_bounds__(256, 2) void fuse_gemm(
    const __hip_bfloat16* __restrict__ wib,   // (1536,512)
    const __hip_bfloat16* __restrict__ weT,   // (128,512)
    __hip_bfloat16* __restrict__ wf)          // (1536,128)
{
  __shared__ __align__(16) __hip_bfloat16 smem[32768];  // 2 x (A 8192 ++ B 8192)

  const int tid  = threadIdx.x;
  const int w    = tid >> 6;
  const int lane = tid & 63;
  const int g0 = blockIdx.x * 128;
  const int wm = (w >> 1) * 64;
  const int wn = (w & 1) * 64;
  const int lrow = lane >> 3;
  const int gc   = ((lane & 7) ^ lrow) * 8;
  const int l15 = lane & 15;
  const int q   = lane >> 4;
  const int sx  = l15 & 7;

  f32x4 acc[4][4];
#pragma unroll
  for (int i = 0; i < 4; ++i)
#pragma unroll
    for (int j = 0; j < 4; ++j) acc[i][j] = (f32x4)0.0f;

  // stage tile 0 -> buf0
#pragma unroll
  for (int c = 0; c < 4; ++c) {
    const int chunk = w * 4 + c;
    const int row = chunk * 8 + lrow;
    async_load16(wib + (size_t)(g0 + row) * HD + gc, (void*)&smem[chunk * 512]);
    async_load16(weT + (size_t)row * HD + gc, (void*)&smem[8192 + chunk * 512]);
  }
  __syncthreads();

#pragma unroll
  for (int t = 0; t < 8; ++t) {
    const __hip_bfloat16* As = smem + (t & 1) * 16384;
    const __hip_bfloat16* Bs = As + 8192;
    if (t < 7) {
      __hip_bfloat16* An = smem + ((t + 1) & 1) * 16384;
      const int k = (t + 1) * 64;
#pragma unroll
      for (int c = 0; c < 4; ++c) {
        const int chunk = w * 4 + c;
        const int row = chunk * 8 + lrow;
        async_load16(wib + (size_t)(g0 + row) * HD + k + gc, (void*)&An[chunk * 512]);
        async_load16(weT + (size_t)row * HD + k + gc, (void*)&An[8192 + chunk * 512]);
      }
    }
    __builtin_amdgcn_sched_barrier(0);
#pragma unroll
    for (int ks = 0; ks < 2; ++ks) {
      const int s = ((ks * 4 + q) ^ sx) * 8;
      bf16x8 af[4], bfr[4];
#pragma unroll
      for (int mi = 0; mi < 4; ++mi)
        af[mi] = *(const bf16x8*)&As[(wm + mi * 16 + l15) * 64 + s];
#pragma unroll
      for (int ni = 0; ni < 4; ++ni)
        bfr[ni] = *(const bf16x8*)&Bs[(wn + ni * 16 + l15) * 64 + s];
      __builtin_amdgcn_s_setprio(1);
#pragma unroll
      for (int ni = 0; ni < 4; ++ni)
#pragma unroll
        for (int mi = 0; mi < 4; ++mi)
          acc[mi][ni] = __builtin_amdgcn_mfma_f32_16x16x32_bf16(
              af[mi], bfr[ni], acc[mi][ni], 0, 0, 0);
      __builtin_amdgcn_s_setprio(0);
    }
    if (t < 7) __syncthreads();
  }

  // Epilogue: bf16 repack through LDS (buf0; last tile read buf1 -> disjoint).
  __hip_bfloat16* ebuf = &smem[w * 4096];
#pragma unroll
  for (int ni = 0; ni < 4; ++ni)
#pragma unroll
    for (int mi = 0; mi < 4; ++mi)
#pragma unroll
      for (int r = 0; r < 4; ++r)
        ebuf[(mi * 16 + q * 4 + r) * 64 + ni * 16 + l15] =
            __float2bfloat16(acc[mi][ni][r]);
#pragma unroll
  for (int i = 0; i < 8; ++i) {
    const int row  = i * 8 + (lane >> 3);
    const int colb = (lane & 7) * 8;
    const bf16x8 v = *(const bf16x8*)&ebuf[row * 64 + colb];
    *(bf16x8*)&wf[(size_t)(g0 + wm + row) * I_DIM + wn + colb] = v;
  }
}

// ---------------------------------------------------------------------------
// gru_main: gi[m, g*512+h] = sum_i x_bf[m,i] * W_fused[g*512+h, i]; gates.
// M=65536, K=128 (2 K-tiles of BK=64), per block 128 M x 64 h x 3 gates.
// 4 waves (2x2): wave = 64M x 32h x 3g -> acc[3][4][2]. LDS dbuf 2x40KB,
// 2 blocks/CU. Structure = r2-proven gru_gemm; epilogue unchanged except
// b_ih -> b_fused.
// ---------------------------------------------------------------------------
__device__ __forceinline__ void main_stage(const __hip_bfloat16* __restrict__ xb,
                                           const __hip_bfloat16* __restrict__ wf,
                                           int m0, int h0, int k,
                                           __hip_bfloat16* As, __hip_bfloat16* Bs,
                                           int w, int lrow, int gc) {
  // A tile: 128 rows -> 16 chunks, 4 per wave (row stride I_DIM=128)
#pragma unroll
  for (int c = 0; c < 4; ++c) {
    const int chunk = w * 4 + c;
    async_load16(xb + (size_t)(m0 + chunk * 8 + lrow) * I_DIM + k + gc,
                 (void*)&As[chunk * 512]);
  }
  // B tiles: per gate 64 rows -> 8 chunks, 2 per wave (row stride 128)
#pragma unroll
  for (int g = 0; g < 3; ++g)
#pragma unroll
    for (int c = 0; c < 2; ++c) {
      const int chunk = w * 2 + c;
      async_load16(wf + (size_t)(g * HD + h0 + chunk * 8 + lrow) * I_DIM + k + gc,
                   (void*)&Bs[g * 4096 + chunk * 512]);
    }
}

__global__ __launch_bounds__(256, 2) void gru_main(
    const __hip_bfloat16* __restrict__ xb,    // (65536,128) bf16
    const __hip_bfloat16* __restrict__ wf,    // (1536,128) bf16
    const float* __restrict__ bfu,            // (1536) fp32  b_fused
    const float* __restrict__ b_hh,           // (1536) fp32
    float* __restrict__ out)                  // H ++ h_last fp32
{
  __shared__ __align__(16) char smem[81920];  // 2 x (As 16K ++ Bs 24K)

  const int tid  = threadIdx.x;
  const int w    = tid >> 6;
  const int lane = tid & 63;
  const int m0 = blockIdx.x * 128;
  const int h0 = blockIdx.y * 64;
  const int wm = (w >> 1) * 64;
  const int wn = (w & 1) * 32;
  const int lrow = lane >> 3;
  const int gc   = ((lane & 7) ^ lrow) * 8;
  const int l15 = lane & 15;
  const int q   = lane >> 4;
  const int sx  = l15 & 7;

  f32x4 acc[3][4][2];
#pragma unroll
  for (int g = 0; g < 3; ++g)
#pragma unroll
    for (int i = 0; i < 4; ++i)
#pragma unroll
      for (int j = 0; j < 2; ++j) acc[g][i][j] = (f32x4)0.0f;

  // prologue: stage K-tile 0 -> buf0
  main_stage(xb, wf, m0, h0, 0,
             (__hip_bfloat16*)smem, (__hip_bfloat16*)(smem + 16384),
             w, lrow, gc);
  __syncthreads();

#pragma unroll
  for (int t = 0; t < 2; ++t) {
    const __hip_bfloat16* As = (const __hip_bfloat16*)(smem + (t & 1) * 40960);
    const __hip_bfloat16* Bs = (const __hip_bfloat16*)(smem + (t & 1) * 40960 + 16384);
    if (t == 0)  // prefetch K-tile 1 -> buf1 under tile-0 compute
      main_stage(xb, wf, m0, h0, 64,
                 (__hip_bfloat16*)(smem + 40960),
                 (__hip_bfloat16*)(smem + 40960 + 16384), w, lrow, gc);
    __builtin_amdgcn_sched_barrier(0);
    bf16x8 af[2][4];
#pragma unroll
    for (int ks = 0; ks < 2; ++ks) {
      const int s = ((ks * 4 + q) ^ sx) * 8;
#pragma unroll
      for (int mi = 0; mi < 4; ++mi)
        af[ks][mi] = *(const bf16x8*)&As[(wm + mi * 16 + l15) * 64 + s];
    }
#pragma unroll
    for (int g = 0; g < 3; ++g) {
      bf16x8 b[2][2];
#pragma unroll
      for (int ks = 0; ks < 2; ++ks) {
        const int s = ((ks * 4 + q) ^ sx) * 8;
#pragma unroll
        for (int ni = 0; ni < 2; ++ni)
          b[ks][ni] = *(const bf16x8*)&Bs[g * 4096 + (wn + ni * 16 + l15) * 64 + s];
      }
      __builtin_amdgcn_s_setprio(1);
#pragma unroll
      for (int ks = 0; ks < 2; ++ks)
#pragma unroll
        for (int ni = 0; ni < 2; ++ni)
#pragma unroll
          for (int mi = 0; mi < 4; ++mi)
            acc[g][mi][ni] = __builtin_amdgcn_mfma_f32_16x16x32_bf16(
                af[ks][mi], b[ks][ni], acc[g][mi][ni], 0, 0, 0);
      __builtin_amdgcn_s_setprio(0);
    }
    if (t == 0) __syncthreads();   // buf1 ready; buf0 reads done
  }

  // Epilogue: gate math (v_rcp), repack wave tile (64M x 32h fp32) through
  // LDS stride 40 floats, float4 stores. obuf in buf0 [0,40960); last tile
  // read buf1 -> disjoint, all waves passed t0's barrier: no barrier needed.
  float* obuf = (float*)(smem + w * 10240);
#pragma unroll
  for (int ni = 0; ni < 2; ++ni) {
    const int col = h0 + wn + ni * 16 + l15;
    const float br = bfu[col] + b_hh[col];
    const float bz = bfu[HD + col] + b_hh[HD + col];
    const float bn = bfu[2 * HD + col];
    const float bhn = b_hh[2 * HD + col];
#pragma unroll
    for (int mi = 0; mi < 4; ++mi) {
#pragma unroll
      for (int r = 0; r < 4; ++r) {
        const float rr = sigf(acc[0][mi][ni][r] + br);
        const float zz = sigf(acc[1][mi][ni][r] + bz);
        const float nn = tanhfast(acc[2][mi][ni][r] + bn + rr * bhn);
        obuf[(mi * 16 + q * 4 + r) * 40 + ni * 16 + l15] = (1.0f - zz) * nn;
      }
    }
  }
  // wave-private region: compiler-inserted lgkmcnt orders write->read
  const int srow = lane >> 3;        // 0..7
  const int scol = (lane & 7) * 4;   // 0,4,...,28
#pragma unroll
  for (int i = 0; i < 8; ++i) {
    const int row = i * 8 + srow;    // m_local 0..63
    const float4 v = *(const float4*)&obuf[row * 40 + scol];
    const int m = m0 + wm + row;
    const int b = m >> 9;            // m / 512
    const int s = m & 511;           // m % 512
    float* dst = (s < 511)
        ? out + (size_t)b * HROW + (size_t)s * HD + h0 + wn + scol
        : out + (size_t)HOFF + (size_t)b * HD + h0 + wn + scol;
    *(float4*)dst = v;
  }
}

extern "C" void kernel_launch(void* const* d_in, const int* in_sizes, int n_in,
                              void* d_out, int out_size, void* d_ws, size_t ws_size,
                              hipStream_t stream) {
  const float* x_f     = (const float*)d_in[0];   // (128,512,128)
  const float* w_emb_f = (const float*)d_in[1];   // (512,128)
  const float* b_emb   = (const float*)d_in[2];   // (512)
  const float* w_ih_f  = (const float*)d_in[3];   // (1536,512)
  const float* b_ih    = (const float*)d_in[4];   // (1536)
  const float* b_hh    = (const float*)d_in[5];   // (1536)
  float* out = (float*)d_out;

  // ws layout (bytes):
  //   [0, 16Mi)                    x bf16      (65536*128*2)
  //   [16Mi, +1.5Mi)               w_ih bf16   (1536*512*2)
  //   [18350080, +128Ki)           w_embT bf16 (128*512*2)
  //   [18481152, +384Ki)           W_fused bf16(1536*128*2)
  //   [18874368, +6Ki)             b_fused f32 (1536*4)
  char* ws = (char*)d_ws;
  __hip_bfloat16* x_bf   = (__hip_bfloat16*)(ws);
  __hip_bfloat16* wi_bf  = (__hip_bfloat16*)(ws + 16777216);
  __hip_bfloat16* weT_bf = (__hip_bfloat16*)(ws + 18350080);
  __hip_bfloat16* wf_bf  = (__hip_bfloat16*)(ws + 18481152);
  float*          b_fu   = (float*)(ws + 18874368);

  prep<<<PB_X + PB_WI + PB_TR + PB_BF, 256, 0, stream>>>(
      x_f, w_emb_f, w_ih_f, b_emb, b_ih, x_bf, weT_bf, wi_bf, b_fu);

  fuse_gemm<<<12, 256, 0, stream>>>(wi_bf, weT_bf, wf_bf);

  gru_main<<<dim3(M_TOT / 128, HD / 64), 256, 0, stream>>>(
      x_bf, wf_bf, b_fu, b_hh, out);
}

// Round 5
// 209.396 us; speedup vs baseline: 1.4377x; 1.0162x over previous
//
#include <hip/hip_runtime.h>
#include <hip/hip_bf16.h>
#include <stdint.h>

// Problem: B=128, S=512, I=128, Hd=512, G=3*Hd=1536, M=B*S=65536.
//
// ALGEBRAIC FUSION (r4, kept): gi = x @ (W_ih@W_emb)^T + (W_ih@b_emb + b_ih)
// -> precompute W_fused (1536x128) + b_fused (1536), one K=128 GEMM + gates.
//
// Round 5: gru_main restructured to read the A-panel ONCE per block:
// grid = 512 M-blocks (no h-split -> A traffic 128MB -> 16MB), A staged to
// LDS once -> MFMA fragments in registers -> A region reused as epilogue
// buffer; B (W_fused) streamed over 16 h-chunks, double-buffered.
#define M_TOT   65536
#define I_DIM   128
#define HD      512
#define HOFF    33488896   // 128*511*512, element offset of h_last in d_out
#define HROW    261632     // 511*512, per-b row stride of H

typedef __bf16 bf16x8 __attribute__((ext_vector_type(8)));
typedef float f32x4 __attribute__((ext_vector_type(4)));

struct __align__(8) bf16x4_t { __hip_bfloat16 v[4]; };

// async global->LDS, 16B per lane (lane-scatter base+lane*16, m104/m108).
__device__ __forceinline__ void async_load16(const void* g, void* l) {
  __builtin_amdgcn_global_load_lds(
      (const __attribute__((address_space(1))) void*)g,
      (__attribute__((address_space(3))) void*)l, 16, 0, 0);
}

// v_rcp_f32: rel err 2^-22 — far below the 1.4e-2 abs threshold.
__device__ __forceinline__ float fastrcp(float x) {
  return __builtin_amdgcn_rcpf(x);
}
__device__ __forceinline__ float sigf(float x) {
  return fastrcp(1.0f + __expf(-x));
}
__device__ __forceinline__ float tanhfast(float x) {
  return 1.0f - 2.0f * fastrcp(__expf(2.0f * x) + 1.0f);
}

// ---------------------------------------------------------------------------
// prep: (a) x f32->bf16, (b) w_ih f32->bf16, (c) w_emb f32 -> w_embT bf16,
// (d) b_fused[g] = b_ih[g] + dot(w_ih[g,:], b_emb). (unchanged from r4)
// ---------------------------------------------------------------------------
#define PB_X   8192
#define PB_WI  768
#define PB_TR  16
#define PB_BF  384
__global__ void prep(const float* __restrict__ x,
                     const float* __restrict__ we,
                     const float* __restrict__ wi,
                     const float* __restrict__ b_emb,
                     const float* __restrict__ b_ih,
                     __hip_bfloat16* __restrict__ xb,
                     __hip_bfloat16* __restrict__ weT,
                     __hip_bfloat16* __restrict__ wib,
                     float* __restrict__ bfu) {
  const int bid = blockIdx.x;
  const int tid = threadIdx.x;
  if (bid < PB_X) {                          // x cvt
    const int i = bid * 256 + tid;
    const float4 v = ((const float4*)x)[i];
    bf16x4_t o;
    o.v[0] = __float2bfloat16(v.x); o.v[1] = __float2bfloat16(v.y);
    o.v[2] = __float2bfloat16(v.z); o.v[3] = __float2bfloat16(v.w);
    ((bf16x4_t*)xb)[i] = o;
  } else if (bid < PB_X + PB_WI) {           // w_ih cvt
    const int i = (bid - PB_X) * 256 + tid;
    const float4 v = ((const float4*)wi)[i];
    bf16x4_t o;
    o.v[0] = __float2bfloat16(v.x); o.v[1] = __float2bfloat16(v.y);
    o.v[2] = __float2bfloat16(v.z); o.v[3] = __float2bfloat16(v.w);
    ((bf16x4_t*)wib)[i] = o;
  } else if (bid < PB_X + PB_WI + PB_TR) {   // w_emb transpose+cvt
    const int b = bid - (PB_X + PB_WI);
    const int i  = b * 8 + (tid >> 5);
    const int h0 = (tid & 31) * 16;
    bf16x8 v0, v1;
#pragma unroll
    for (int j = 0; j < 8; ++j) {
      v0[j] = (__bf16)we[(size_t)(h0 + j) * I_DIM + i];
      v1[j] = (__bf16)we[(size_t)(h0 + 8 + j) * I_DIM + i];
    }
    *(bf16x8*)&weT[(size_t)i * HD + h0] = v0;
    *(bf16x8*)&weT[(size_t)i * HD + h0 + 8] = v1;
  } else {                                   // b_fused: one wave per g
    const int g = (bid - (PB_X + PB_WI + PB_TR)) * 4 + (tid >> 6);
    const int lane = tid & 63;
    const float4* row = (const float4*)(wi + (size_t)g * HD);
    const float4* be  = (const float4*)b_emb;
    float s = 0.0f;
#pragma unroll
    for (int j = 0; j < 2; ++j) {
      const float4 a = row[lane * 2 + j];
      const float4 b = be[lane * 2 + j];
      s += a.x * b.x + a.y * b.y + a.z * b.z + a.w * b.w;
    }
#pragma unroll
    for (int off = 32; off > 0; off >>= 1) s += __shfl_down(s, off);
    if (lane == 0) bfu[g] = s + b_ih[g];
  }
}

// ---------------------------------------------------------------------------
// fuse_gemm: W_fused[g,i] = sum_h w_ih_bf[g,h] * w_embT_bf[i,h]
// M=1536, N=128, K=512. (unchanged from r4)
// ---------------------------------------------------------------------------
__global__ __launch_bounds__(256, 2) void fuse_gemm(
    const __hip_bfloat16* __restrict__ wib,   // (1536,512)
    const __hip_bfloat16* __restrict__ weT,   // (128,512)
    __hip_bfloat16* __restrict__ wf)          // (1536,128)
{
  __shared__ __align__(16) __hip_bfloat16 smem[32768];

  const int tid  = threadIdx.x;
  const int w    = tid >> 6;
  const int lane = tid & 63;
  const int g0 = blockIdx.x * 128;
  const int wm = (w >> 1) * 64;
  const int wn = (w & 1) * 64;
  const int lrow = lane >> 3;
  const int gc   = ((lane & 7) ^ lrow) * 8;
  const int l15 = lane & 15;
  const int q   = lane >> 4;
  const int sx  = l15 & 7;

  f32x4 acc[4][4];
#pragma unroll
  for (int i = 0; i < 4; ++i)
#pragma unroll
    for (int j = 0; j < 4; ++j) acc[i][j] = (f32x4)0.0f;

#pragma unroll
  for (int c = 0; c < 4; ++c) {
    const int chunk = w * 4 + c;
    const int row = chunk * 8 + lrow;
    async_load16(wib + (size_t)(g0 + row) * HD + gc, (void*)&smem[chunk * 512]);
    async_load16(weT + (size_t)row * HD + gc, (void*)&smem[8192 + chunk * 512]);
  }
  __syncthreads();

#pragma unroll
  for (int t = 0; t < 8; ++t) {
    const __hip_bfloat16* As = smem + (t & 1) * 16384;
    const __hip_bfloat16* Bs = As + 8192;
    if (t < 7) {
      __hip_bfloat16* An = smem + ((t + 1) & 1) * 16384;
      const int k = (t + 1) * 64;
#pragma unroll
      for (int c = 0; c < 4; ++c) {
        const int chunk = w * 4 + c;
        const int row = chunk * 8 + lrow;
        async_load16(wib + (size_t)(g0 + row) * HD + k + gc, (void*)&An[chunk * 512]);
        async_load16(weT + (size_t)row * HD + k + gc, (void*)&An[8192 + chunk * 512]);
      }
    }
    __builtin_amdgcn_sched_barrier(0);
#pragma unroll
    for (int ks = 0; ks < 2; ++ks) {
      const int s = ((ks * 4 + q) ^ sx) * 8;
      bf16x8 af[4], bfr[4];
#pragma unroll
      for (int mi = 0; mi < 4; ++mi)
        af[mi] = *(const bf16x8*)&As[(wm + mi * 16 + l15) * 64 + s];
#pragma unroll
      for (int ni = 0; ni < 4; ++ni)
        bfr[ni] = *(const bf16x8*)&Bs[(wn + ni * 16 + l15) * 64 + s];
      __builtin_amdgcn_s_setprio(1);
#pragma unroll
      for (int ni = 0; ni < 4; ++ni)
#pragma unroll
        for (int mi = 0; mi < 4; ++mi)
          acc[mi][ni] = __builtin_amdgcn_mfma_f32_16x16x32_bf16(
              af[mi], bfr[ni], acc[mi][ni], 0, 0, 0);
      __builtin_amdgcn_s_setprio(0);
    }
    if (t < 7) __syncthreads();
  }

  __hip_bfloat16* ebuf = &smem[w * 4096];
#pragma unroll
  for (int ni = 0; ni < 4; ++ni)
#pragma unroll
    for (int mi = 0; mi < 4; ++mi)
#pragma unroll
      for (int r = 0; r < 4; ++r)
        ebuf[(mi * 16 + q * 4 + r) * 64 + ni * 16 + l15] =
            __float2bfloat16(acc[mi][ni][r]);
#pragma unroll
  for (int i = 0; i < 8; ++i) {
    const int row  = i * 8 + (lane >> 3);
    const int colb = (lane & 7) * 8;
    const bf16x8 v = *(const bf16x8*)&ebuf[row * 64 + colb];
    *(bf16x8*)&wf[(size_t)(g0 + wm + row) * I_DIM + wn + colb] = v;
  }
}

// ---------------------------------------------------------------------------
// gru_main (round 5): gi[m, g*512+h] = sum_i x_bf[m,i]*W_fused[g*512+h,i].
// Grid = 512 blocks (128 M-rows each, ALL 512 h) = exactly 2 blocks/CU.
// 4 waves x 32 M-rows. A-panel (128x128) staged to LDS once as two half-K
// [128][64] tiles -> fragments to registers (af[4ks][2mi]); A region then
// reused as the per-wave epilogue repack buffer.
// B streamed over 16 h-chunks of 32 h (x3 gates = 96 rows), stored as two
// half-K [96][64] tiles (12KB each) per buffer, double-buffered (2x24KB).
// LDS total = 32K + 48K = 80KB -> 2 blocks/CU.
// Per chunk: stage next (6 loads/wave) | 24 ds_read_b128 | 48 MFMA (setprio)
// | gate math | repack (wave-private) | float4 stores | __syncthreads.
// ---------------------------------------------------------------------------
__device__ __forceinline__ void stage_B32(const __hip_bfloat16* __restrict__ wf,
                                          int hc, char* Bbuf,
                                          int w, int lrow, int gc) {
  const int h0 = hc * 32;
#pragma unroll
  for (int j = 0; j < 6; ++j) {
    const int idx = w * 6 + j;          // 0..23
    const int kh = idx / 12;            // K-half
    const int cr = idx % 12;            // 8-row chunk within [96]
    const int r  = cr * 8 + lrow;       // 0..95
    const int g  = r >> 5;              // gate
    const int hh = r & 31;              // h within chunk
    async_load16(wf + (size_t)(g * HD + h0 + hh) * I_DIM + kh * 64 + gc,
                 (void*)&((__hip_bfloat16*)Bbuf)[kh * 6144 + cr * 512]);
  }
}

__global__ __launch_bounds__(256, 2) void gru_main(
    const __hip_bfloat16* __restrict__ xb,    // (65536,128) bf16
    const __hip_bfloat16* __restrict__ wf,    // (1536,128) bf16
    const float* __restrict__ bfu,            // (1536) fp32  b_fused
    const float* __restrict__ b_hh,           // (1536) fp32
    float* __restrict__ out)                  // H ++ h_last fp32
{
  // [0,32768): A halves (2 x [128][64]); [32768,+24K) B buf0; [57344,+24K) buf1
  __shared__ __align__(16) char smem[81920];
  __hip_bfloat16* A0 = (__hip_bfloat16*)smem;

  const int tid  = threadIdx.x;
  const int w    = tid >> 6;
  const int lane = tid & 63;
  const int m0 = blockIdx.x * 128;
  const int wm = w * 32;                     // wave M-offset
  const int lrow = lane >> 3;
  const int gc   = ((lane & 7) ^ lrow) * 8;  // swizzled global element offset
  const int l15 = lane & 15;
  const int q   = lane >> 4;
  const int sx  = l15 & 7;

  // one-time A stage (both K-halves) + first B chunk
#pragma unroll
  for (int kh = 0; kh < 2; ++kh)
#pragma unroll
    for (int c = 0; c < 4; ++c) {
      const int chunk = w * 4 + c;
      async_load16(xb + (size_t)(m0 + chunk * 8 + lrow) * I_DIM + kh * 64 + gc,
                   (void*)&A0[kh * 8192 + chunk * 512]);
    }
  stage_B32(wf, 0, smem + 32768, w, lrow, gc);
  __syncthreads();                            // A + B(0) resident

  // A fragments to registers: af[ks][mi], ks = K-slice 0..3, mi = M 0..1
  bf16x8 af[4][2];
#pragma unroll
  for (int ks = 0; ks < 4; ++ks) {
    const int half = ks >> 1;
    const int s = (((ks & 1) * 4 + q) ^ sx) * 8;
#pragma unroll
    for (int mi = 0; mi < 2; ++mi)
      af[ks][mi] = *(const bf16x8*)&A0[half * 8192 + (wm + mi * 16 + l15) * 64 + s];
  }
  __syncthreads();   // ALL waves done reading A -> A region reusable as obuf

  float* obuf = (float*)(smem + w * 8192);    // wave-private, in A region
  const int srow = lane >> 3;
  const int scol = (lane & 7) * 4;

#pragma unroll 2
  for (int hc = 0; hc < 16; ++hc) {
    const __hip_bfloat16* Bs =
        (const __hip_bfloat16*)(smem + 32768 + (hc & 1) * 24576);
    if (hc < 15)
      stage_B32(wf, hc + 1, smem + 32768 + ((hc + 1) & 1) * 24576, w, lrow, gc);
    __builtin_amdgcn_sched_barrier(0);        // pin stage issue at chunk top

    f32x4 acc[3][2][2];
#pragma unroll
    for (int g = 0; g < 3; ++g)
#pragma unroll
      for (int mi = 0; mi < 2; ++mi)
#pragma unroll
        for (int ni = 0; ni < 2; ++ni) acc[g][mi][ni] = (f32x4)0.0f;

    __builtin_amdgcn_s_setprio(1);
#pragma unroll
    for (int g = 0; g < 3; ++g)
#pragma unroll
      for (int ks = 0; ks < 4; ++ks) {
        const int half = ks >> 1;
        const int s = (((ks & 1) * 4 + q) ^ sx) * 8;
#pragma unroll
        for (int ni = 0; ni < 2; ++ni) {
          const bf16x8 bv =
              *(const bf16x8*)&Bs[half * 6144 + (g * 32 + ni * 16 + l15) * 64 + s];
#pragma unroll
          for (int mi = 0; mi < 2; ++mi)
            acc[g][mi][ni] = __builtin_amdgcn_mfma_f32_16x16x32_bf16(
                af[ks][mi], bv, acc[g][mi][ni], 0, 0, 0);
        }
      }
    __builtin_amdgcn_s_setprio(0);

    // gate math + wave-private repack (stride 40 floats) + float4 stores
    const int h0 = hc * 32;
#pragma unroll
    for (int ni = 0; ni < 2; ++ni) {
      const int col = h0 + ni * 16 + l15;
      const float br = bfu[col] + b_hh[col];
      const float bz = bfu[HD + col] + b_hh[HD + col];
      const float bn = bfu[2 * HD + col];
      const float bhn = b_hh[2 * HD + col];
#pragma unroll
      for (int mi = 0; mi < 2; ++mi) {
#pragma unroll
        for (int r = 0; r < 4; ++r) {
          const float rr = sigf(acc[0][mi][ni][r] + br);
          const float zz = sigf(acc[1][mi][ni][r] + bz);
          const float nn = tanhfast(acc[2][mi][ni][r] + bn + rr * bhn);
          obuf[(mi * 16 + q * 4 + r) * 40 + ni * 16 + l15] = (1.0f - zz) * nn;
        }
      }
    }
    // wave-private obuf: compiler lgkmcnt orders write->read
#pragma unroll
    for (int i = 0; i < 4; ++i) {
      const int row = i * 8 + srow;           // m_local 0..31
      const float4 v = *(const float4*)&obuf[row * 40 + scol];
      const int m = m0 + wm + row;
      const int b = m >> 9;                   // m / 512
      const int s = m & 511;                  // m % 512
      float* dst = (s < 511)
          ? out + (size_t)b * HROW + (size_t)s * HD + h0 + scol
          : out + (size_t)HOFF + (size_t)b * HD + h0 + scol;
      *(float4*)dst = v;
    }
    __syncthreads();   // staging drained (vmcnt0) + B reads done -> swap safe
  }
}

extern "C" void kernel_launch(void* const* d_in, const int* in_sizes, int n_in,
                              void* d_out, int out_size, void* d_ws, size_t ws_size,
                              hipStream_t stream) {
  const float* x_f     = (const float*)d_in[0];   // (128,512,128)
  const float* w_emb_f = (const float*)d_in[1];   // (512,128)
  const float* b_emb   = (const float*)d_in[2];   // (512)
  const float* w_ih_f  = (const float*)d_in[3];   // (1536,512)
  const float* b_ih    = (const float*)d_in[4];   // (1536)
  const float* b_hh    = (const float*)d_in[5];   // (1536)
  float* out = (float*)d_out;

  // ws layout (bytes):
  //   [0, 16Mi)            x bf16      (65536*128*2)
  //   [16Mi, +1.5Mi)       w_ih bf16   (1536*512*2)
  //   [18350080, +128Ki)   w_embT bf16 (128*512*2)
  //   [18481152, +384Ki)   W_fused bf16(1536*128*2)
  //   [18874368, +6Ki)     b_fused f32 (1536*4)
  char* ws = (char*)d_ws;
  __hip_bfloat16* x_bf   = (__hip_bfloat16*)(ws);
  __hip_bfloat16* wi_bf  = (__hip_bfloat16*)(ws + 16777216);
  __hip_bfloat16* weT_bf = (__hip_bfloat16*)(ws + 18350080);
  __hip_bfloat16* wf_bf  = (__hip_bfloat16*)(ws + 18481152);
  float*          b_fu   = (float*)(ws + 18874368);

  prep<<<PB_X + PB_WI + PB_TR + PB_BF, 256, 0, stream>>>(
      x_f, w_emb_f, w_ih_f, b_emb, b_ih, x_bf, weT_bf, wi_bf, b_fu);

  fuse_gemm<<<12, 256, 0, stream>>>(wi_bf, weT_bf, wf_bf);

  gru_main<<<M_TOT / 128, 256, 0, stream>>>(x_bf, wf_bf, b_fu, b_hh, out);
}